// Round 12
// baseline (643.453 us; speedup 1.0000x reference)
//
#include <hip/hip_runtime.h>

#define NN 50000
#define EE 250000
#define HD 128

typedef __attribute__((ext_vector_type(8))) _Float16 f16x8;
typedef __attribute__((ext_vector_type(4))) _Float16 f16x4;
typedef __attribute__((ext_vector_type(4))) float f32x4;

// ---------------- CSR build (both graphs in one launch) ----------------
__global__ void hist2_kernel(const int* __restrict__ row1, const int* __restrict__ row2,
                             int* __restrict__ cnt) {
    int t = blockIdx.x * blockDim.x + threadIdx.x;
    if (t >= 2 * EE) return;
    int g = t >= EE;
    int e = t - g * EE;
    const int* row = g ? row2 : row1;
    atomicAdd(&cnt[g * NN + row[e]], 1);
}

__global__ __launch_bounds__(1024) void scan2_kernel(const int* __restrict__ cnt_all,
                                                     int* __restrict__ rp1,
                                                     int* __restrict__ rp2) {
    __shared__ int s[1024];
    const int* cnt = cnt_all + blockIdx.x * NN;
    int* rp = blockIdx.x ? rp2 : rp1;
    int tid = threadIdx.x;
    int c0 = 0;
    for (int base = 0; base < NN; base += 8192) {
        int v[8];
        int sum = 0;
        int i0 = base + tid * 8;
#pragma unroll
        for (int j = 0; j < 8; ++j) {
            int i = i0 + j;
            v[j] = (i < NN) ? cnt[i] : 0;
            sum += v[j];
        }
        s[tid] = sum;
        __syncthreads();
        for (int off = 1; off < 1024; off <<= 1) {
            int t2 = (tid >= off) ? s[tid - off] : 0;
            __syncthreads();
            s[tid] += t2;
            __syncthreads();
        }
        int excl = c0 + s[tid] - sum;
#pragma unroll
        for (int j = 0; j < 8; ++j) {
            int i = i0 + j;
            if (i < NN) rp[i] = excl;
            excl += v[j];
        }
        int tot = s[1023];
        __syncthreads();
        c0 += tot;
    }
    if (tid == 0) rp[NN] = c0;
}

// stores interleaved (col, val-bits) per edge: 1 load/edge in spmm
__global__ void scatter2_kernel(const int* __restrict__ row1, const int* __restrict__ col1,
                                const float* __restrict__ val1, const int* __restrict__ row2,
                                const int* __restrict__ col2, const float* __restrict__ val2,
                                const int* __restrict__ rp1, const int* __restrict__ rp2,
                                int* __restrict__ cur, int2* __restrict__ ev1,
                                int2* __restrict__ ev2) {
    int t = blockIdx.x * blockDim.x + threadIdx.x;
    if (t >= 2 * EE) return;
    int g = t >= EE;
    int e = t - g * EE;
    const int* row = g ? row2 : row1;
    const int* col = g ? col2 : col1;
    const float* val = g ? val2 : val1;
    const int* rp = g ? rp2 : rp1;
    int2* ev = g ? ev2 : ev1;
    int r = row[e];
    int p = atomicAdd(&cur[g * NN + r], 1);
    int d = rp[r] + p;
    ev[d] = make_int2(col[e], __builtin_bit_cast(int, val[e]));
}

// ---------------- weight pack (fp16, MFMA fragment order, one launch) ----------------
__device__ inline void pack_one(const float* __restrict__ in, _Float16* __restrict__ out,
                                int NCOL, int NKS, int t) {
    int lane = t & 63, f = t >> 6;
    int ks = f % NKS, ct = f / NKS;
    int nl = lane & 15, kg = lane >> 4;
    int c = ct * 16 + nl;
    f16x8 o;
#pragma unroll
    for (int j = 0; j < 8; ++j) {
        int k = ks * 32 + kg * 8 + j;
        o[j] = (_Float16)in[k * NCOL + c];
    }
    *(f16x8*)(out + f * 512 + lane * 8) = o;
}

__global__ void pack_all_kernel(const float* __restrict__ L1w, _Float16* __restrict__ W1p,
                                const float* __restrict__ L2w, _Float16* __restrict__ W2p,
                                const float* __restrict__ Wg0, const float* __restrict__ Wg1,
                                const float* __restrict__ Wg2, const float* __restrict__ Wg3,
                                _Float16* __restrict__ Wp0, _Float16* __restrict__ Wp1,
                                _Float16* __restrict__ Wp2, _Float16* __restrict__ Wp3) {
    int t = blockIdx.x * 256 + threadIdx.x;
    if (t < 4096) {
        pack_one(L1w, W1p, 256, 4, t);
    } else if (t < 12288) {
        pack_one(L2w, W2p, 256, 8, t - 4096);
    } else if (t < 20480) {
        int u = t - 12288;
        int l = u >> 11;  // 2048 per layer
        int tt = u & 2047;
        const float* in = l == 0 ? Wg0 : l == 1 ? Wg1 : l == 2 ? Wg2 : Wg3;
        _Float16* out = l == 0 ? Wp0 : l == 1 ? Wp1 : l == 2 ? Wp2 : Wp3;
        pack_one(in, out, 128, 4, tt);
    }
}

__global__ void cvt_w0_kernel(const float* __restrict__ in, _Float16* __restrict__ out) {
    int t = blockIdx.x * 256 + threadIdx.x;
    int i = t * 8;
    if (i >= NN * HD) return;
    float4 a = *(const float4*)(in + i);
    float4 b = *(const float4*)(in + i + 4);
    f16x8 h;
    h[0] = (_Float16)a.x; h[1] = (_Float16)a.y; h[2] = (_Float16)a.z; h[3] = (_Float16)a.w;
    h[4] = (_Float16)b.x; h[5] = (_Float16)b.y; h[6] = (_Float16)b.z; h[7] = (_Float16)b.w;
    *(f16x8*)(out + i) = h;
}

// ---------------- SpMM layer-1 (both graphs): xf = l2norm(relu(A @ W0h)) ----------------
// 4 rows/wave, 16 lanes x fp16x8 (16B/lane); edge loop unrolled x8 branch-free.
__global__ __launch_bounds__(256) void spmm_norm_kernel(
    const int* __restrict__ rp1, const int2* __restrict__ ev1, const int* __restrict__ rp2,
    const int2* __restrict__ ev2, const _Float16* __restrict__ xin,
    _Float16* __restrict__ xf1, _Float16* __restrict__ xf2) {
    int rr = (blockIdx.x * 256 + threadIdx.x) >> 4;
    int ln = threadIdx.x & 15;
    if (rr >= 2 * NN) return;
    int g = rr >= NN;
    int r = rr - g * NN;
    const int* rp = g ? rp2 : rp1;
    const int2* ev = g ? ev2 : ev1;
    _Float16* xf = g ? xf2 : xf1;
    int beg = rp[r], end = rp[r + 1];
    float acc[8] = {};
    for (int e = beg; e < end; e += 8) {
#pragma unroll
        for (int i = 0; i < 8; ++i) {
            int ei = e + i;
            int idx = ei < end ? ei : end - 1;
            int2 cv = ev[idx];
            float v = ei < end ? __builtin_bit_cast(float, cv.y) : 0.f;
            f16x8 xr = *(const f16x8*)(xin + (size_t)cv.x * HD + ln * 8);
#pragma unroll
            for (int j = 0; j < 8; ++j) acc[j] = fmaf(v, (float)xr[j], acc[j]);
        }
    }
    float ss = 0.f;
#pragma unroll
    for (int j = 0; j < 8; ++j) {
        acc[j] = fmaxf(acc[j], 0.f);
        ss = fmaf(acc[j], acc[j], ss);
    }
#pragma unroll
    for (int off = 1; off < 16; off <<= 1) ss += __shfl_xor(ss, off, 64);
    float sc = 1.f / fmaxf(sqrtf(ss), 1e-12f);
    f16x8 hf;
#pragma unroll
    for (int j = 0; j < 8; ++j) hf[j] = (_Float16)(acc[j] * sc);
    *(f16x8*)(xf + (size_t)r * HD + ln * 8) = hf;
}

// ---------------- SpMM raw (both graphs): z = A @ xf16 (fp16 out) ----------------
__global__ __launch_bounds__(256) void spmm_raw_kernel(
    const int* __restrict__ rp1, const int2* __restrict__ ev1, const int* __restrict__ rp2,
    const int2* __restrict__ ev2, const _Float16* __restrict__ xf1,
    const _Float16* __restrict__ xf2, _Float16* __restrict__ z1, _Float16* __restrict__ z2) {
    int rr = (blockIdx.x * 256 + threadIdx.x) >> 4;
    int ln = threadIdx.x & 15;
    if (rr >= 2 * NN) return;
    int g = rr >= NN;
    int r = rr - g * NN;
    const int* rp = g ? rp2 : rp1;
    const int2* ev = g ? ev2 : ev1;
    const _Float16* xin = g ? xf2 : xf1;
    _Float16* z = g ? z2 : z1;
    int beg = rp[r], end = rp[r + 1];
    float acc[8] = {};
    for (int e = beg; e < end; e += 8) {
#pragma unroll
        for (int i = 0; i < 8; ++i) {
            int ei = e + i;
            int idx = ei < end ? ei : end - 1;
            int2 cv = ev[idx];
            float v = ei < end ? __builtin_bit_cast(float, cv.y) : 0.f;
            f16x8 xr = *(const f16x8*)(xin + (size_t)cv.x * HD + ln * 8);
#pragma unroll
            for (int j = 0; j < 8; ++j) acc[j] = fmaf(v, (float)xr[j], acc[j]);
        }
    }
    f16x8 h;
#pragma unroll
    for (int j = 0; j < 8; ++j) h[j] = (_Float16)acc[j];
    *(f16x8*)(z + (size_t)r * HD + ln * 8) = h;
}

// ---------------- fused GEMM + MLP (fp16 MFMA, both graphs in one grid) ----------------
// __launch_bounds__(256,4): 4 waves/SIMD = 16 waves/CU = 4 blocks/CU
// (LDS 4x34.8KB=139KB<160KB, VGPR 128 budget >= 84 used)
__global__ __launch_bounds__(256, 4) void gemm_mlp_kernel(
    const _Float16* __restrict__ z1, const _Float16* __restrict__ z2,
    const _Float16* __restrict__ Wp, const _Float16* __restrict__ W1p,
    const float* __restrict__ L1b, const _Float16* __restrict__ W2p,
    const float* __restrict__ L2b, const float* __restrict__ L3w,
    const float* __restrict__ L3b, _Float16* __restrict__ xf1, _Float16* __restrict__ xf2,
    float* __restrict__ s1, float* __restrict__ s2, int ngrid, int do_norm, int write_x) {
    __shared__ __align__(16) char U[32768];  // Xt (16KB) then reused as H1s (32KB)
    __shared__ float redss[4][64];
    __shared__ float red[4][64];
    char* Xt = U;
    char* H1s = U;
    int tid = threadIdx.x;
    int wave = tid >> 6, lane = tid & 63;
    int nl = lane & 15, kg = lane >> 4;
    int g = blockIdx.x >= ngrid;
    int tile = (blockIdx.x - g * ngrid) * 64;
    const _Float16* z = g ? z2 : z1;
    _Float16* xfout = g ? xf2 : xf1;
    float* score = g ? s2 : s1;

    // ===== GEMM phase: x = [l2norm](relu(z @ W)) =====
    f16x8 ah[4][4];
#pragma unroll
    for (int m = 0; m < 4; ++m) {
        int node = tile + m * 16 + nl;
        if (node >= NN) node = NN - 1;
        const _Float16* ph = z + (size_t)node * HD + kg * 8;
#pragma unroll
        for (int ks = 0; ks < 4; ++ks) ah[m][ks] = *(const f16x8*)(ph + ks * 32);
    }

    f32x4 acc[2][4];
#pragma unroll
    for (int c = 0; c < 2; ++c) {
        int ct = wave * 2 + c;
        f16x8 wh[4];
#pragma unroll
        for (int ks = 0; ks < 4; ++ks)
            wh[ks] = *(const f16x8*)(Wp + (ct * 4 + ks) * 512 + lane * 8);
#pragma unroll
        for (int m = 0; m < 4; ++m) acc[c][m] = (f32x4){0.f, 0.f, 0.f, 0.f};
#pragma unroll
        for (int ks = 0; ks < 4; ++ks)
#pragma unroll
            for (int m = 0; m < 4; ++m)
                acc[c][m] = __builtin_amdgcn_mfma_f32_16x16x32_f16(wh[ks], ah[m][ks], acc[c][m], 0, 0, 0);
    }
#pragma unroll
    for (int c = 0; c < 2; ++c)
#pragma unroll
        for (int m = 0; m < 4; ++m)
#pragma unroll
            for (int r = 0; r < 4; ++r) acc[c][m][r] = fmaxf(acc[c][m][r], 0.f);

    float scale[4] = {1.f, 1.f, 1.f, 1.f};
    if (do_norm) {
        float ss[4];
#pragma unroll
        for (int m = 0; m < 4; ++m) {
            float s = 0.f;
#pragma unroll
            for (int c = 0; c < 2; ++c)
#pragma unroll
                for (int r = 0; r < 4; ++r) s = fmaf(acc[c][m][r], acc[c][m][r], s);
            s += __shfl_xor(s, 16, 64);
            s += __shfl_xor(s, 32, 64);
            ss[m] = s;
        }
        if (kg == 0) {
#pragma unroll
            for (int m = 0; m < 4; ++m) redss[wave][m * 16 + nl] = ss[m];
        }
        __syncthreads();
#pragma unroll
        for (int m = 0; m < 4; ++m) {
            int r = m * 16 + nl;
            float tot = redss[0][r] + redss[1][r] + redss[2][r] + redss[3][r];
            scale[m] = 1.f / fmaxf(sqrtf(tot), 1e-12f);
        }
    }

    // x-tile to LDS (fp16, swizzled, stride 256B) + fp16 global
#pragma unroll
    for (int c = 0; c < 2; ++c) {
        int ct = wave * 2 + c;
#pragma unroll
        for (int m = 0; m < 4; ++m) {
            f16x4 hs;
            hs[0] = (_Float16)(acc[c][m][0] * scale[m]);
            hs[1] = (_Float16)(acc[c][m][1] * scale[m]);
            hs[2] = (_Float16)(acc[c][m][2] * scale[m]);
            hs[3] = (_Float16)(acc[c][m][3] * scale[m]);
            int r = m * 16 + nl;
            int byte = (r * 256 + ct * 32 + kg * 8) ^ ((r & 7) << 4);
            *(f16x4*)(Xt + byte) = hs;
            int node = tile + r;
            if (write_x && node < NN)
                *(f16x4*)(xfout + (size_t)node * HD + ct * 16 + kg * 4) = hs;
        }
    }
    __syncthreads();

    // ===== MLP phase =====
    f16x8 a1[4][4];
#pragma unroll
    for (int m = 0; m < 4; ++m) {
        int r = m * 16 + nl;
#pragma unroll
        for (int ks = 0; ks < 4; ++ks) {
            int byte = (r * 256 + ks * 64 + kg * 16) ^ ((r & 7) << 4);
            a1[m][ks] = *(const f16x8*)(Xt + byte);
        }
    }
    __syncthreads();  // all A1 reads done before H1s overwrites the union

#pragma unroll
    for (int c = 0; c < 4; ++c) {
        int ct = wave * 4 + c;
        f16x8 w[4];
#pragma unroll
        for (int ks = 0; ks < 4; ++ks)
            w[ks] = *(const f16x8*)(W1p + (ct * 4 + ks) * 512 + lane * 8);
        f32x4 a[4];
#pragma unroll
        for (int m = 0; m < 4; ++m) a[m] = (f32x4){0.f, 0.f, 0.f, 0.f};
#pragma unroll
        for (int ks = 0; ks < 4; ++ks)
#pragma unroll
            for (int m = 0; m < 4; ++m)
                a[m] = __builtin_amdgcn_mfma_f32_16x16x32_f16(w[ks], a1[m][ks], a[m], 0, 0, 0);
        float4 b1v = *(const float4*)(L1b + ct * 16 + kg * 4);
#pragma unroll
        for (int m = 0; m < 4; ++m) {
            f16x4 hs;
            hs[0] = (_Float16)fmaxf(a[m][0] + b1v.x, 0.f);
            hs[1] = (_Float16)fmaxf(a[m][1] + b1v.y, 0.f);
            hs[2] = (_Float16)fmaxf(a[m][2] + b1v.z, 0.f);
            hs[3] = (_Float16)fmaxf(a[m][3] + b1v.w, 0.f);
            int r = m * 16 + nl;
            int byte = (r * 512 + ct * 32 + kg * 8) ^ ((r & 7) << 4);
            *(f16x4*)(H1s + byte) = hs;
        }
    }
    __syncthreads();

    f16x8 a2[4][8];
#pragma unroll
    for (int m = 0; m < 4; ++m) {
        int r = m * 16 + nl;
#pragma unroll
        for (int ks = 0; ks < 8; ++ks) {
            int byte = (r * 512 + ks * 64 + kg * 16) ^ ((r & 7) << 4);
            a2[m][ks] = *(const f16x8*)(H1s + byte);
        }
    }

    float t[4] = {0.f, 0.f, 0.f, 0.f};
#pragma unroll
    for (int c = 0; c < 4; ++c) {
        int ct = wave * 4 + c;
        f16x8 w[8];
#pragma unroll
        for (int ks = 0; ks < 8; ++ks)
            w[ks] = *(const f16x8*)(W2p + (ct * 8 + ks) * 512 + lane * 8);
        f32x4 a[4];
#pragma unroll
        for (int m = 0; m < 4; ++m) a[m] = (f32x4){0.f, 0.f, 0.f, 0.f};
#pragma unroll
        for (int ks = 0; ks < 8; ++ks)
#pragma unroll
            for (int m = 0; m < 4; ++m)
                a[m] = __builtin_amdgcn_mfma_f32_16x16x32_f16(w[ks], a2[m][ks], a[m], 0, 0, 0);
        float4 b2v = *(const float4*)(L2b + ct * 16 + kg * 4);
        float4 w3v = *(const float4*)(L3w + ct * 16 + kg * 4);
#pragma unroll
        for (int m = 0; m < 4; ++m) {
            t[m] = fmaf(fmaxf(a[m][0] + b2v.x, 0.f), w3v.x, t[m]);
            t[m] = fmaf(fmaxf(a[m][1] + b2v.y, 0.f), w3v.y, t[m]);
            t[m] = fmaf(fmaxf(a[m][2] + b2v.z, 0.f), w3v.z, t[m]);
            t[m] = fmaf(fmaxf(a[m][3] + b2v.w, 0.f), w3v.w, t[m]);
        }
    }
#pragma unroll
    for (int m = 0; m < 4; ++m) {
        t[m] += __shfl_xor(t[m], 16, 64);
        t[m] += __shfl_xor(t[m], 32, 64);
    }
    if (kg == 0) {
#pragma unroll
        for (int m = 0; m < 4; ++m) red[wave][m * 16 + nl] = t[m];
    }
    __syncthreads();
    if (tid < 64) {
        int gg = tile + tid;
        if (gg < NN) {
            float s = red[0][tid] + red[1][tid] + red[2][tid] + red[3][tid];
            score[gg] += s + L3b[0];
        }
    }
}

// ---------------- standalone MLP (layer-1 path, both graphs), score = ----------------
__global__ __launch_bounds__(256, 4) void mlp_mfma_kernel(
    const _Float16* __restrict__ xf1, const _Float16* __restrict__ xf2,
    const _Float16* __restrict__ W1p, const float* __restrict__ L1b,
    const _Float16* __restrict__ W2p, const float* __restrict__ L2b,
    const float* __restrict__ L3w, const float* __restrict__ L3b, float* __restrict__ s1,
    float* __restrict__ s2, int ngrid) {
    __shared__ __align__(16) char H1s[32768];
    __shared__ float red[4][64];
    int tid = threadIdx.x;
    int wave = tid >> 6, lane = tid & 63;
    int nl = lane & 15, kg = lane >> 4;
    int g = blockIdx.x >= ngrid;
    int tile = (blockIdx.x - g * ngrid) * 64;
    const _Float16* xf = g ? xf2 : xf1;
    float* score = g ? s2 : s1;

    f16x8 a1[4][4];
#pragma unroll
    for (int m = 0; m < 4; ++m) {
        int node = tile + m * 16 + nl;
        if (node >= NN) node = NN - 1;
        const _Float16* xr = xf + (size_t)node * HD + kg * 8;
#pragma unroll
        for (int ks = 0; ks < 4; ++ks) a1[m][ks] = *(const f16x8*)(xr + ks * 32);
    }

#pragma unroll
    for (int c = 0; c < 4; ++c) {
        int ct = wave * 4 + c;
        f16x8 w[4];
#pragma unroll
        for (int ks = 0; ks < 4; ++ks)
            w[ks] = *(const f16x8*)(W1p + (ct * 4 + ks) * 512 + lane * 8);
        f32x4 a[4];
#pragma unroll
        for (int m = 0; m < 4; ++m) a[m] = (f32x4){0.f, 0.f, 0.f, 0.f};
#pragma unroll
        for (int ks = 0; ks < 4; ++ks)
#pragma unroll
            for (int m = 0; m < 4; ++m)
                a[m] = __builtin_amdgcn_mfma_f32_16x16x32_f16(w[ks], a1[m][ks], a[m], 0, 0, 0);
        float4 b1v = *(const float4*)(L1b + ct * 16 + kg * 4);
#pragma unroll
        for (int m = 0; m < 4; ++m) {
            f16x4 hs;
            hs[0] = (_Float16)fmaxf(a[m][0] + b1v.x, 0.f);
            hs[1] = (_Float16)fmaxf(a[m][1] + b1v.y, 0.f);
            hs[2] = (_Float16)fmaxf(a[m][2] + b1v.z, 0.f);
            hs[3] = (_Float16)fmaxf(a[m][3] + b1v.w, 0.f);
            int r = m * 16 + nl;
            int byte = (r * 512 + ct * 32 + kg * 8) ^ ((r & 7) << 4);
            *(f16x4*)(H1s + byte) = hs;
        }
    }
    __syncthreads();

    f16x8 a2[4][8];
#pragma unroll
    for (int m = 0; m < 4; ++m) {
        int r = m * 16 + nl;
#pragma unroll
        for (int ks = 0; ks < 8; ++ks) {
            int byte = (r * 512 + ks * 64 + kg * 16) ^ ((r & 7) << 4);
            a2[m][ks] = *(const f16x8*)(H1s + byte);
        }
    }

    float t[4] = {0.f, 0.f, 0.f, 0.f};
#pragma unroll
    for (int c = 0; c < 4; ++c) {
        int ct = wave * 4 + c;
        f16x8 w[8];
#pragma unroll
        for (int ks = 0; ks < 8; ++ks)
            w[ks] = *(const f16x8*)(W2p + (ct * 8 + ks) * 512 + lane * 8);
        f32x4 a[4];
#pragma unroll
        for (int m = 0; m < 4; ++m) a[m] = (f32x4){0.f, 0.f, 0.f, 0.f};
#pragma unroll
        for (int ks = 0; ks < 8; ++ks)
#pragma unroll
            for (int m = 0; m < 4; ++m)
                a[m] = __builtin_amdgcn_mfma_f32_16x16x32_f16(w[ks], a2[m][ks], a[m], 0, 0, 0);
        float4 b2v = *(const float4*)(L2b + ct * 16 + kg * 4);
        float4 w3v = *(const float4*)(L3w + ct * 16 + kg * 4);
#pragma unroll
        for (int m = 0; m < 4; ++m) {
            t[m] = fmaf(fmaxf(a[m][0] + b2v.x, 0.f), w3v.x, t[m]);
            t[m] = fmaf(fmaxf(a[m][1] + b2v.y, 0.f), w3v.y, t[m]);
            t[m] = fmaf(fmaxf(a[m][2] + b2v.z, 0.f), w3v.z, t[m]);
            t[m] = fmaf(fmaxf(a[m][3] + b2v.w, 0.f), w3v.w, t[m]);
        }
    }
#pragma unroll
    for (int m = 0; m < 4; ++m) {
        t[m] += __shfl_xor(t[m], 16, 64);
        t[m] += __shfl_xor(t[m], 32, 64);
    }
    if (kg == 0) {
#pragma unroll
        for (int m = 0; m < 4; ++m) red[wave][m * 16 + nl] = t[m];
    }
    __syncthreads();
    if (tid < 64) {
        int gg = tile + tid;
        if (gg < NN) {
            float s = red[0][tid] + red[1][tid] + red[2][tid] + red[3][tid];
            score[gg] = s + L3b[0];  // first MLP writes (no memset needed)
        }
    }
}

__global__ void final_kernel(const float* __restrict__ s1, const float* __restrict__ s2,
                             float* __restrict__ out) {
    int i = blockIdx.x * blockDim.x + threadIdx.x;
    if (i < NN) out[i] = s1[i] * s2[i];
}

extern "C" void kernel_launch(void* const* d_in, const int* in_sizes, int n_in,
                              void* d_out, int out_size, void* d_ws, size_t ws_size,
                              hipStream_t stream) {
    const int* row1 = (const int*)d_in[0];
    const int* col1 = (const int*)d_in[1];
    const float* val1 = (const float*)d_in[2];
    const int* row2 = (const int*)d_in[3];
    const int* col2 = (const int*)d_in[4];
    const float* val2 = (const float*)d_in[5];
    const float* W0 = (const float*)d_in[6];
    const float* Wg[4] = {(const float*)d_in[7], (const float*)d_in[8], (const float*)d_in[9],
                          (const float*)d_in[10]};
    const float* L1w = (const float*)d_in[11];
    const float* L1b = (const float*)d_in[12];
    const float* L2w = (const float*)d_in[13];
    const float* L2b = (const float*)d_in[14];
    const float* L3w = (const float*)d_in[15];
    const float* L3b = (const float*)d_in[16];
    float* out = (float*)d_out;

    char* ws = (char*)d_ws;
    size_t off = 0;
    auto alloc = [&](size_t bytes) {
        void* p = ws + off;
        off = (off + bytes + 255) & ~(size_t)255;
        return p;
    };
    int* rp1 = (int*)alloc((NN + 1) * 4);
    int* rp2 = (int*)alloc((NN + 1) * 4);
    int2* ev1 = (int2*)alloc((size_t)EE * 8);
    int2* ev2 = (int2*)alloc((size_t)EE * 8);
    int* cntcur = (int*)alloc(4 * NN * 4);
    float* s1 = (float*)alloc(NN * 4);
    float* s2 = (float*)alloc(NN * 4);
    _Float16* xf1 = (_Float16*)alloc((size_t)NN * HD * 2);
    _Float16* xf2 = (_Float16*)alloc((size_t)NN * HD * 2);
    _Float16* w0h = (_Float16*)alloc((size_t)NN * HD * 2);
    _Float16* z1 = (_Float16*)alloc((size_t)NN * HD * 2);
    _Float16* z2 = (_Float16*)alloc((size_t)NN * HD * 2);
    _Float16* W1p = (_Float16*)alloc(16 * 4 * 512 * 2);
    _Float16* W2p = (_Float16*)alloc(16 * 8 * 512 * 2);
    _Float16* Wp[4];
    for (int l = 0; l < 4; ++l) Wp[l] = (_Float16*)alloc(8 * 4 * 512 * 2);
    int* cnt = cntcur;
    int* cur = cntcur + 2 * NN;

    // ---- prep ----
    pack_all_kernel<<<80, 256, 0, stream>>>(L1w, W1p, L2w, W2p, Wg[0], Wg[1], Wg[2], Wg[3],
                                            Wp[0], Wp[1], Wp[2], Wp[3]);
    cvt_w0_kernel<<<(NN * HD / 8 + 255) / 256, 256, 0, stream>>>(W0, w0h);
    hipMemsetAsync(cntcur, 0, 4 * NN * 4, stream);
    hist2_kernel<<<(2 * EE + 255) / 256, 256, 0, stream>>>(row1, row2, cnt);
    scan2_kernel<<<2, 1024, 0, stream>>>(cnt, rp1, rp2);
    scatter2_kernel<<<(2 * EE + 255) / 256, 256, 0, stream>>>(row1, col1, val1, row2, col2,
                                                              val2, rp1, rp2, cur, ev1, ev2);

    int spmm_grid = (2 * NN * 16 + 255) / 256;
    int ngrid = (NN + 63) / 64;
    spmm_norm_kernel<<<spmm_grid, 256, 0, stream>>>(rp1, ev1, rp2, ev2, w0h, xf1, xf2);
    mlp_mfma_kernel<<<2 * ngrid, 256, 0, stream>>>(xf1, xf2, W1p, L1b, W2p, L2b, L3w, L3b, s1,
                                                   s2, ngrid);
    for (int l = 0; l < 4; ++l) {
        spmm_raw_kernel<<<spmm_grid, 256, 0, stream>>>(rp1, ev1, rp2, ev2, xf1, xf2, z1, z2);
        gemm_mlp_kernel<<<2 * ngrid, 256, 0, stream>>>(z1, z2, Wp[l], W1p, L1b, W2p, L2b, L3w,
                                                       L3b, xf1, xf2, s1, s2, ngrid,
                                                       l < 3 ? 1 : 0, l < 3 ? 1 : 0);
    }

    final_kernel<<<(NN + 255) / 256, 256, 0, stream>>>(s1, s2, out);
}